// Round 10
// baseline (356.166 us; speedup 1.0000x reference)
//
#include <hip/hip_runtime.h>
#include <math.h>

// Problem: images [64,256,256] f32 -> patches [16384][256] f32 (identity perm)
//          tokens [16384] = argmin_v ||patch - vocab[v]||^2, vocab [4096][256] f32
#define PS      16
#define D       256
#define V       4096
#define M       16384
#define NSPLIT  64              // V / 64 column groups
#define PAIR_CAP 1048576
// Scores packed as u32 keys: q = (u32)((s + 1024) * 512)  (20 bits), key =
// (q << 12) | col. min() on keys = argmin with lowest-index tie-break.
// fp16 score-diff error sigma ~3e-2; QMARGIN 130 quanta (=0.254) is ~8 sigma
// incl. trunc slack. Flagged (~4%) get exact fp64 on a candidate set provably
// containing the argmin.
#define QMARGIN 130

typedef _Float16 half8 __attribute__((ext_vector_type(8)));
typedef _Float16 half4 __attribute__((ext_vector_type(4)));
typedef float    f32x4 __attribute__((ext_vector_type(4)));

__device__ __forceinline__ void gload_lds16(const void* g, void* l) {
  __builtin_amdgcn_global_load_lds(
      (const __attribute__((address_space(1))) unsigned int*)g,
      (__attribute__((address_space(3))) unsigned int*)l, 16, 0, 0);
}

// Fragment-major layouts (halves):
//  Ah2[rowblk(256)][kt(8)][i(4)][q(4)][cl(16)][8] : row = rowblk*64+i*16+cl,
//      k = kt*32 + q*8 + h.   idx = rowblk*16384 + kt*2048 + i*512 + q*128 + cl*8 + h
//  Vh2[sp'(16)][kt(8)][jb(16)][q(4)][cl(16)][8]   : col = sp'*256+jb*16+cl,
//      k = kt*32 + q*8 + h.   idx = sp'*65536 + kt*8192 + jb*512 + q*128 + cl*8 + h

// ---------------------------------------------------------------------------
// Kernel 1: fused prep. Blocks [0,4096): patchify (float4) + fragment-major
// fp16 copy. Blocks [4096,5120): vocab fragment-major fp16 + v2.
// ---------------------------------------------------------------------------
__global__ __launch_bounds__(256) void prep_kernel(
    const float* __restrict__ img, const float* __restrict__ vocab,
    float* __restrict__ outp, _Float16* __restrict__ Ah2,
    _Float16* __restrict__ Vh2, float* __restrict__ v2,
    int* __restrict__ paircount) {
  if (blockIdx.x < 4096) {
    if (blockIdx.x == 0 && threadIdx.x == 0) *paircount = 0;
    const int t  = blockIdx.x * 256 + threadIdx.x;   // M*D/4 threads
    const int o4 = t << 2;
    const int m   = o4 >> 8;           // global patch index
    const int d   = o4 & 255;          // k (multiple of 4)
    const int b   = m >> 8;
    const int n   = m & 255;
    const int py = n >> 4, px = n & 15, i = d >> 4, j = d & 15;
    const float4 v = *(const float4*)(img + (b << 16) + ((py * PS + i) << 8) + px * PS + j);
    *(float4*)(outp + o4) = v;
    half4 h = { (_Float16)v.x, (_Float16)v.y, (_Float16)v.z, (_Float16)v.w };
    const int fa = (m >> 6) * 16384 + (d >> 5) * 2048 + ((m >> 4) & 3) * 512 +
                   ((d >> 3) & 3) * 128 + (m & 15) * 8 + (d & 7);
    *(half4*)(Ah2 + fa) = h;
  } else {
    const int gtid = (blockIdx.x - 4096) * 256 + threadIdx.x;
    const int c    = gtid >> 6;        // vocab row
    const int lane = gtid & 63;
    const int d0   = lane << 2;        // k (multiple of 4)
    const float4 v = *(const float4*)(vocab + (size_t)c * D + d0);
    half4 h = { (_Float16)v.x, (_Float16)v.y, (_Float16)v.z, (_Float16)v.w };
    const int fv = (c >> 8) * 65536 + (d0 >> 5) * 8192 + ((c >> 4) & 15) * 512 +
                   ((d0 >> 3) & 3) * 128 + (c & 15) * 8 + (d0 & 7);
    *(half4*)(Vh2 + fv) = h;
    float s = v.x * v.x + v.y * v.y + v.z * v.z + v.w * v.w;
    #pragma unroll
    for (int off = 32; off > 0; off >>= 1) s += __shfl_down(s, off);
    if (lane == 0) v2[c] = s;
  }
}

// ---------------------------------------------------------------------------
// Kernel 2: fp16 MFMA score GEMM — R22: 16-wave (1024-thread) blocks over
// one 32KB A-tile -> 2 blocks/CU x 16 waves = 32 waves/CU = 8 waves/SIMD,
// the hardware cap. Session ledger: occupancy is the ONLY lever that moved
// this kernel (R16: 4->8 waves/block = -17%); schedule edits x3 neutral,
// tiling x2 negative, 32x32 shape negative (acc-chain ILP loss). Per-wave
// code identical to R18/R21 (32 cols/wave, half-tile bp ping-pong K-loop,
// deferred q-merge) -> bit-identical pk1/pk2. launch_bounds(1024,8) pins
// the 8-wave VGPR budget (<=64; current 40). Merge: 8 wid-pairs, scr
// 2x16KB reuses Af exactly.
// Block = 64 rows x 512 cols (16 waves x 32 cols); grid (sp=8 FAST, rowblk).
// ---------------------------------------------------------------------------
__global__ __launch_bounds__(1024, 8) void gemm_score_kernel(
    const _Float16* __restrict__ Ah2,  // fragment-major, see layout above
    const _Float16* __restrict__ Vh2,
    const float* __restrict__ v2,
    unsigned* __restrict__ pk1, unsigned* __restrict__ pk2) {
  __shared__ __align__(16) _Float16 Af[8 * 64 * 32];  // 32 KB A tile (= scr1+scr2 after K-loop)

  const int tid  = threadIdx.x;
  const int lane = tid & 63;
  const int wid  = tid >> 6;                // 0..15
  const int sp     = blockIdx.x;            // 512-col block, FAST dim (A L2 reuse)
  const int rowblk = blockIdx.y;
  const int row0 = rowblk * 64;
  const int c0w  = sp * 512 + wid * 32;     // this wave's 32 vocab cols

  // ---- stage A tile: 16 waves x 2 x (64 lanes x 16B contiguous), one barrier ----
  {
    const _Float16* src = Ah2 + (size_t)rowblk * 16384 + wid * 1024 + lane * 8;
    _Float16* dst = Af + wid * 1024;        // wave-uniform; HW adds lane*16B
    #pragma unroll
    for (int t = 0; t < 2; ++t)
      gload_lds16(src + t * 512, dst + t * 512);
  }
  __syncthreads();

  const int cl = lane & 15;           // fragment row/col within 16
  const int q  = lane >> 4;           // quad: k-chunk selector
  const _Float16* Ak = Af + q * 128 + cl * 8;                    // patch frags (B-op)
  const _Float16* Bk = Vh2 + (c0w >> 8) * 65536 + ((c0w >> 4) & 15) * 512 +
                       q * 128 + cl * 8;                          // vocab frags (A-op)

  f32x4 acc[2][4];                    // [i = vocab tile][j = patch tile]
  #pragma unroll
  for (int i = 0; i < 2; ++i)
    #pragma unroll
    for (int j = 0; j < 4; ++j) acc[i][j] = (f32x4){0.f, 0.f, 0.f, 0.f};

  // K-loop: av (global V) ping-pong, bp split into half-tiles (bpA = j0,j1;
  // bpB = j2,j3) each prefetched one 4-MFMA cluster ahead. Static names only.
  half8 av0[2], av1[2], a0[2], a1[2], b0[2], b1[2];
#define LAV(B, OFF) do {                                            \
    B[0] = *(const half8*)(Bk + (OFF));                             \
    B[1] = *(const half8*)(Bk + (OFF) + 512);                       \
  } while (0)
#define LBH(P, OFF) do {                                            \
    P[0] = *(const half8*)(Ak + (OFF));                             \
    P[1] = *(const half8*)(Ak + (OFF) + 512);                       \
  } while (0)
#define MM4(AV, P, J0, J1) do {                                     \
    __builtin_amdgcn_s_setprio(1);                                  \
    acc[0][J0] = __builtin_amdgcn_mfma_f32_16x16x32_f16(AV[0], P[0], acc[0][J0], 0, 0, 0); \
    acc[0][J1] = __builtin_amdgcn_mfma_f32_16x16x32_f16(AV[0], P[1], acc[0][J1], 0, 0, 0); \
    acc[1][J0] = __builtin_amdgcn_mfma_f32_16x16x32_f16(AV[1], P[0], acc[1][J0], 0, 0, 0); \
    acc[1][J1] = __builtin_amdgcn_mfma_f32_16x16x32_f16(AV[1], P[1], acc[1][J1], 0, 0, 0); \
    __builtin_amdgcn_s_setprio(0);                                  \
  } while (0)

  LAV(av0, 0);                        // kt=0 V operands
  LBH(a0, 0);                         // kt=0 bpA (j0,j1)
  #pragma unroll 1
  for (int kt2 = 0; kt2 < 3; ++kt2) { // kt = {0,1},{2,3},{4,5}
    LAV(av1, 8192);                   // V kt+1
    LBH(b0, 1024);                    // bpB kt
    MM4(av0, a0, 0, 1);               // kt even, j0/j1
    LBH(a1, 2048);                    // bpA kt+1
    MM4(av0, b0, 2, 3);               // kt even, j2/j3
    LAV(av0, 16384);                  // V kt+2 (kt2=2 -> kt=6, in bounds)
    LBH(b1, 3072);                    // bpB kt+1
    MM4(av1, a1, 0, 1);               // kt odd, j0/j1
    LBH(a0, 4096);                    // bpA kt+2 (kt2=2 -> kt=6, in bounds)
    MM4(av1, b1, 2, 3);               // kt odd, j2/j3
    Bk += 16384; Ak += 4096;
  }
  // kt = 6,7 peeled (no dead prefetch past Vh2); a0 holds kt=6 bpA, av0 kt=6 V
  LAV(av1, 8192);                     // kt=7 V
  LBH(b0, 1024);                      // kt=6 bpB
  MM4(av0, a0, 0, 1);
  LBH(a1, 2048);                      // kt=7 bpA
  MM4(av0, b0, 2, 3);
  LBH(b1, 3072);                      // kt=7 bpB
  MM4(av1, a1, 0, 1);
  MM4(av1, b1, 2, 3);
#undef LAV
#undef LBH
#undef MM4

  // Epilogue (S^T). Lane (cl,q) holds, for patch row m = row0 + j*16 + cl,
  // scores of vocab cols v = c0w + i*16 + q*4 + r.
  // key_f = (score+1024)*512 = (v2+1024)*512 - 1024*acc
  float Cv[8];
  #pragma unroll
  for (int i = 0; i < 2; ++i) {
    const float4 vq = *(const float4*)(v2 + c0w + i * 16 + q * 4);
    #pragma unroll
    for (int r = 0; r < 4; ++r) Cv[i * 4 + r] = fmaf(vq[r], 512.0f, 524288.0f);
  }
  // Per-lane top-2 over this lane's 8 cols per j. NO cross-lane shuffles:
  // q-merge deferred to the LDS pass (top-2 union-fold is order-independent;
  // keys unique via embedded col -> bit-identical pk1/pk2).
  unsigned wk1[4], wk2[4];
  #pragma unroll
  for (int j = 0; j < 4; ++j) {
    unsigned K1 = 0xFFFFFFFFu, K2 = 0xFFFFFFFFu;
    #pragma unroll
    for (int i = 0; i < 2; ++i)
      #pragma unroll
      for (int r = 0; r < 4; ++r) {
        const unsigned key =
            ((unsigned)fmaf(-1024.0f, acc[i][j][r], Cv[i * 4 + r]) << 12) |
            (unsigned)(c0w + i * 16 + q * 4 + r);
        K2 = min(K2, max(K1, key));
        K1 = min(K1, key);
      }
    wk1[j] = K1; wk2[j] = K2;
  }
  // ---- merge via Af-as-scratch: scr1/scr2 [wid(16)][row(64)][q(4)] u32 ----
  // 16KB each = exactly Af. Write banks: (cl*4+q)%32 -> 2-way = free (m136).
  __syncthreads();                    // all waves finished ds_reads of Af
  unsigned* scr1 = (unsigned*)Af;     // 16 KB
  unsigned* scr2 = scr1 + 4096;       // 16 KB
  #pragma unroll
  for (int j = 0; j < 4; ++j) {
    const int idx = wid * 256 + (j * 16 + cl) * 4 + q;
    scr1[idx] = wk1[j]; scr2[idx] = wk2[j];
  }
  __syncthreads();
  if (tid < 512) {
    const int pair = tid >> 6, row = tid & 63;   // pair 0..7 = wid pairs
    unsigned K1 = 0xFFFFFFFFu, K2 = 0xFFFFFFFFu;
    #pragma unroll
    for (int w = 0; w < 2; ++w) {
      const int base = (pair * 2 + w) * 256 + row * 4;
      #pragma unroll
      for (int qq = 0; qq < 4; ++qq) {
        const unsigned b1 = scr1[base + qq], b2 = scr2[base + qq];
        K2 = min(min(K2, b2), max(K1, b1));
        K1 = min(K1, b1);
      }
    }
    const int grp = sp * 8 + pair;               // 0..63
    pk1[(size_t)grp * M + row0 + row] = K1;
    pk2[(size_t)grp * M + row0 + row] = K2;
  }
}

// ---------------------------------------------------------------------------
// Kernel 3: merge NSPLIT partials -> token; flagged patches emit fp64-rescore
// candidate pairs. 4 waves each scan 16 splits for 64 patches, LDS merge,
// wave 0 finishes (flag path rereads pk, ~4% only).
// ---------------------------------------------------------------------------
__global__ __launch_bounds__(256) void reduce_gather_kernel(
    const unsigned* __restrict__ pk1, const unsigned* __restrict__ pk2,
    float* __restrict__ tok, unsigned long long* __restrict__ minkey,
    unsigned* __restrict__ pairs, int* __restrict__ paircount) {
  __shared__ unsigned r1[4][64], r2[4][64];
  const int tid = threadIdx.x;
  const int mo  = tid & 63;
  const int wid = tid >> 6;
  const int m = blockIdx.x * 64 + mo;
  unsigned K1 = 0xFFFFFFFFu, K2 = 0xFFFFFFFFu;
  for (int s = wid * 16; s < wid * 16 + 16; ++s) {
    const unsigned b1 = pk1[(size_t)s * M + m];
    const unsigned b2 = pk2[(size_t)s * M + m];
    K2 = min(min(K2, b2), max(K1, b1));
    K1 = min(K1, b1);
  }
  r1[wid][mo] = K1; r2[wid][mo] = K2;
  __syncthreads();
  if (tid < 64) {
    K1 = 0xFFFFFFFFu; K2 = 0xFFFFFFFFu;
    #pragma unroll
    for (int w = 0; w < 4; ++w) {
      const unsigned b1 = r1[w][mo], b2 = r2[w][mo];
      K2 = min(min(K2, b2), max(K1, b1));
      K1 = min(K1, b1);
    }
    tok[m] = (float)(K1 & 4095u);
    minkey[m] = 0xFFFFFFFFFFFFFFFFull;
    if ((int)(K2 >> 12) - (int)(K1 >> 12) <= QMARGIN) {
      const int th = (int)(K1 >> 12) + QMARGIN;
      int cnt = 0;
      for (int s = 0; s < NSPLIT; ++s) {
        const unsigned b1 = pk1[(size_t)s * M + m];
        const unsigned b2 = pk2[(size_t)s * M + m];
        cnt += ((int)(b2 >> 12) <= th) ? 64
             : (((int)(b1 >> 12) <= th) ? 1 : 0);
      }
      int base = atomicAdd(paircount, cnt);
      if (base + cnt <= PAIR_CAP) {
        const unsigned mh = (unsigned)m << 12;
        for (int s = 0; s < NSPLIT; ++s) {
          const unsigned b1 = pk1[(size_t)s * M + m];
          const unsigned b2 = pk2[(size_t)s * M + m];
          if ((int)(b2 >> 12) <= th) {        // group may hide a 3rd contender
            for (int r = 0; r < 64; ++r) pairs[base + r] = mh | (unsigned)(s * 64 + r);
            base += 64;
          } else if ((int)(b1 >> 12) <= th) { // only stored winner qualifies
            pairs[base++] = mh | (b1 & 4095u);
          }
        }
      }
    }
  }
}

// ---------------------------------------------------------------------------
// Kernel 4: exact fp64 rescore, one wave per pair, single pass.
// key = (bits(d2) & ~0xFFF) | row: atomicMin = argmin with low-index
// tie-break; 12 dropped mantissa bits = ~1e-9 abs tolerance (safe).
// ---------------------------------------------------------------------------
__global__ __launch_bounds__(256) void refine_score(
    const float* __restrict__ patches, const float* __restrict__ vocab,
    const unsigned* __restrict__ pairs, const int* __restrict__ paircount,
    unsigned long long* __restrict__ minkey) {
  const int lane = threadIdx.x & 63;
  const int gw = (blockIdx.x * 256 + threadIdx.x) >> 6;
  const int nw = (gridDim.x * 256) >> 6;
  int np = *paircount;
  if (np > PAIR_CAP) np = PAIR_CAP;
  for (int i = gw; i < np; i += nw) {
    const unsigned pr = pairs[i];
    const int m = pr >> 12, row = pr & 4095;
    const float4 pv = *(const float4*)(patches + (size_t)m * D + (lane << 2));
    const float4 vv = *(const float4*)(vocab + (size_t)row * D + (lane << 2));
    double acc = 0.0, df;
    df = (double)pv.x - (double)vv.x; acc = fma(df, df, acc);
    df = (double)pv.y - (double)vv.y; acc = fma(df, df, acc);
    df = (double)pv.z - (double)vv.z; acc = fma(df, df, acc);
    df = (double)pv.w - (double)vv.w; acc = fma(df, df, acc);
    #pragma unroll
    for (int off = 32; off > 0; off >>= 1) acc += __shfl_down(acc, off);
    if (lane == 0) {
      const unsigned long long key =
          ((unsigned long long)__double_as_longlong(acc) & ~0xFFFull) | (unsigned)row;
      atomicMin(&minkey[m], key);
    }
  }
}

// ---------------------------------------------------------------------------
// Kernel 5: write refined tokens (grid-stride over pairs; redundant same-value
// writes per flagged patch are benign).
// ---------------------------------------------------------------------------
__global__ __launch_bounds__(256) void refine_final(
    const unsigned* __restrict__ pairs, const int* __restrict__ paircount,
    const unsigned long long* __restrict__ minkey, float* __restrict__ tok) {
  int np = *paircount;
  if (np > PAIR_CAP) np = PAIR_CAP;
  for (int i = blockIdx.x * 256 + threadIdx.x; i < np; i += gridDim.x * 256) {
    const int m = pairs[i] >> 12;
    tok[m] = (float)(unsigned)(minkey[m] & 4095ull);
  }
}

// ---------------------------------------------------------------------------
extern "C" void kernel_launch(void* const* d_in, const int* in_sizes, int n_in,
                              void* d_out, int out_size, void* d_ws, size_t ws_size,
                              hipStream_t stream) {
  const float* images = (const float*)d_in[0];   // [64,256,256]
  const float* vocab  = (const float*)d_in[1];   // [4096,256]
  float* out     = (float*)d_out;
  float* patches = out;            // M*D floats
  float* tokens  = out + (size_t)M * D;

  // workspace layout (bytes):
  // Ah2 8MB | Vh2 2MB | v2 16KB | pk1 4MB | pk2 4MB | minkey 128KB |
  // paircount 64B | pairs 4MB   (~22.3 MB)
  char* ws = (char*)d_ws;
  _Float16* Ah2      = (_Float16*)(ws);
  _Float16* Vh2      = (_Float16*)(ws + 8388608);
  float*    v2       = (float*)   (ws + 10485760);
  unsigned* pk1      = (unsigned*)(ws + 10502144);
  unsigned* pk2      = (unsigned*)(ws + 14696448);
  unsigned long long* minkey = (unsigned long long*)(ws + 18890752);
  int*      paircount= (int*)     (ws + 19021824);
  unsigned* pairs    = (unsigned*)(ws + 19021888);

  prep_kernel<<<4096 + 1024, 256, 0, stream>>>(images, vocab, patches, Ah2,
                                               Vh2, v2, paircount);
  gemm_score_kernel<<<dim3(V / 512, M / 64), 1024, 0, stream>>>(Ah2, Vh2, v2, pk1, pk2);
  reduce_gather_kernel<<<M / 64, 256, 0, stream>>>(pk1, pk2, tokens, minkey,
                                                   pairs, paircount);
  refine_score<<<2048, 256, 0, stream>>>(patches, vocab, pairs, paircount, minkey);
  refine_final<<<64, 256, 0, stream>>>(pairs, paircount, minkey, tokens);
}

// Round 11
// 150.288 us; speedup vs baseline: 2.3699x; 2.3699x over previous
//
#include <hip/hip_runtime.h>
#include <math.h>

// Problem: images [64,256,256] f32 -> patches [16384][256] f32 (identity perm)
//          tokens [16384] = argmin_v ||patch - vocab[v]||^2, vocab [4096][256] f32
#define PS      16
#define D       256
#define V       4096
#define M       16384
#define NSPLIT  64              // V / 64 column groups
#define PAIR_CAP 1048576
// Scores packed as u32 keys: q = (u32)((s + 1024) * 512)  (20 bits), key =
// (q << 12) | col. min() on keys = argmin with lowest-index tie-break.
// fp16 score-diff error sigma ~3e-2; QMARGIN 130 quanta (=0.254) is ~8 sigma
// incl. trunc slack. Flagged (~4%) get exact fp64 on a candidate set provably
// containing the argmin.
#define QMARGIN 130

typedef _Float16 half8 __attribute__((ext_vector_type(8)));
typedef _Float16 half4 __attribute__((ext_vector_type(4)));
typedef float    f32x4 __attribute__((ext_vector_type(4)));

__device__ __forceinline__ void gload_lds16(const void* g, void* l) {
  __builtin_amdgcn_global_load_lds(
      (const __attribute__((address_space(1))) unsigned int*)g,
      (__attribute__((address_space(3))) unsigned int*)l, 16, 0, 0);
}

// Fragment-major layouts (halves):
//  Ah2[rowblk(256)][kt(8)][i(4)][q(4)][cl(16)][8] : row = rowblk*64+i*16+cl,
//      k = kt*32 + q*8 + h.   idx = rowblk*16384 + kt*2048 + i*512 + q*128 + cl*8 + h
//  Vh2[sp'(16)][kt(8)][jb(16)][q(4)][cl(16)][8]   : col = sp'*256+jb*16+cl,
//      k = kt*32 + q*8 + h.   idx = sp'*65536 + kt*8192 + jb*512 + q*128 + cl*8 + h

// ---------------------------------------------------------------------------
// Kernel 1: fused prep. Blocks [0,4096): patchify (float4) + fragment-major
// fp16 copy. Blocks [4096,5120): vocab fragment-major fp16 + v2.
// ---------------------------------------------------------------------------
__global__ __launch_bounds__(256) void prep_kernel(
    const float* __restrict__ img, const float* __restrict__ vocab,
    float* __restrict__ outp, _Float16* __restrict__ Ah2,
    _Float16* __restrict__ Vh2, float* __restrict__ v2,
    int* __restrict__ paircount) {
  if (blockIdx.x < 4096) {
    if (blockIdx.x == 0 && threadIdx.x == 0) *paircount = 0;
    const int t  = blockIdx.x * 256 + threadIdx.x;   // M*D/4 threads
    const int o4 = t << 2;
    const int m   = o4 >> 8;           // global patch index
    const int d   = o4 & 255;          // k (multiple of 4)
    const int b   = m >> 8;
    const int n   = m & 255;
    const int py = n >> 4, px = n & 15, i = d >> 4, j = d & 15;
    const float4 v = *(const float4*)(img + (b << 16) + ((py * PS + i) << 8) + px * PS + j);
    *(float4*)(outp + o4) = v;
    half4 h = { (_Float16)v.x, (_Float16)v.y, (_Float16)v.z, (_Float16)v.w };
    const int fa = (m >> 6) * 16384 + (d >> 5) * 2048 + ((m >> 4) & 3) * 512 +
                   ((d >> 3) & 3) * 128 + (m & 15) * 8 + (d & 7);
    *(half4*)(Ah2 + fa) = h;
  } else {
    const int gtid = (blockIdx.x - 4096) * 256 + threadIdx.x;
    const int c    = gtid >> 6;        // vocab row
    const int lane = gtid & 63;
    const int d0   = lane << 2;        // k (multiple of 4)
    const float4 v = *(const float4*)(vocab + (size_t)c * D + d0);
    half4 h = { (_Float16)v.x, (_Float16)v.y, (_Float16)v.z, (_Float16)v.w };
    const int fv = (c >> 8) * 65536 + (d0 >> 5) * 8192 + ((c >> 4) & 15) * 512 +
                   ((d0 >> 3) & 3) * 128 + (c & 15) * 8 + (d0 & 7);
    *(half4*)(Vh2 + fv) = h;
    float s = v.x * v.x + v.y * v.y + v.z * v.z + v.w * v.w;
    #pragma unroll
    for (int off = 32; off > 0; off >>= 1) s += __shfl_down(s, off);
    if (lane == 0) v2[c] = s;
  }
}

// ---------------------------------------------------------------------------
// Kernel 2: fp16 MFMA score GEMM — R23 = R18/R21 revert (best measured:
// 151.0 us total). Structure: R16 8-wave blocks (6 waves/SIMD, 32KB A-tile
// via global_load_lds, one barrier), R17 deferred q-merge epilogue, R18
// half-tile bp ping-pong + av global ping-pong K-loop, 16x16x32 shape.
// Session frontier (both sides measured): 6 waves/SIMD @ ~80 live regs is
// the max — R22's (1024,8) forced the 64-reg budget and spilled the
// accumulators (WRITE_SIZE 8MB->778MB, MfmaUtil 5%). 32x32 shape loses
// acc-chain ILP (R20, -12%). Schedule edits at this occupancy: neutral.
// Block = 64 rows x 256 cols (8 waves x 32 cols); grid (sp=16 FAST, rowblk).
// ---------------------------------------------------------------------------
__global__ __launch_bounds__(512, 6) void gemm_score_kernel(
    const _Float16* __restrict__ Ah2,  // fragment-major, see layout above
    const _Float16* __restrict__ Vh2,
    const float* __restrict__ v2,
    unsigned* __restrict__ pk1, unsigned* __restrict__ pk2) {
  __shared__ __align__(16) _Float16 Af[8 * 64 * 32];  // 32 KB A tile (+ 16KB scratch after K-loop)

  const int tid  = threadIdx.x;
  const int lane = tid & 63;
  const int wid  = tid >> 6;                // 0..7
  const int sp     = blockIdx.x;            // 256-col block, FAST dim (A L2 reuse)
  const int rowblk = blockIdx.y;
  const int row0 = rowblk * 64;
  const int c0w  = sp * 256 + wid * 32;     // this wave's 32 vocab cols

  // ---- stage A tile: 8 waves x 4 x (64 lanes x 16B contiguous), one barrier ----
  {
    const _Float16* src = Ah2 + (size_t)rowblk * 16384 + wid * 2048 + lane * 8;
    _Float16* dst = Af + wid * 2048;        // wave-uniform; HW adds lane*16B
    #pragma unroll
    for (int t = 0; t < 4; ++t)
      gload_lds16(src + t * 512, dst + t * 512);
  }
  __syncthreads();

  const int cl = lane & 15;           // fragment row/col within 16
  const int q  = lane >> 4;           // quad: k-chunk selector
  const _Float16* Ak = Af + q * 128 + cl * 8;                    // patch frags (B-op)
  const _Float16* Bk = Vh2 + sp * 65536 + wid * 1024 +
                       q * 128 + cl * 8;                          // vocab frags (A-op)

  f32x4 acc[2][4];                    // [i = vocab tile][j = patch tile]
  #pragma unroll
  for (int i = 0; i < 2; ++i)
    #pragma unroll
    for (int j = 0; j < 4; ++j) acc[i][j] = (f32x4){0.f, 0.f, 0.f, 0.f};

  // K-loop: av (global V) ping-pong, bp split into half-tiles (bpA = j0,j1;
  // bpB = j2,j3) each prefetched one 4-MFMA cluster ahead. Static names only.
  half8 av0[2], av1[2], a0[2], a1[2], b0[2], b1[2];
#define LAV(B, OFF) do {                                            \
    B[0] = *(const half8*)(Bk + (OFF));                             \
    B[1] = *(const half8*)(Bk + (OFF) + 512);                       \
  } while (0)
#define LBH(P, OFF) do {                                            \
    P[0] = *(const half8*)(Ak + (OFF));                             \
    P[1] = *(const half8*)(Ak + (OFF) + 512);                       \
  } while (0)
#define MM4(AV, P, J0, J1) do {                                     \
    __builtin_amdgcn_s_setprio(1);                                  \
    acc[0][J0] = __builtin_amdgcn_mfma_f32_16x16x32_f16(AV[0], P[0], acc[0][J0], 0, 0, 0); \
    acc[0][J1] = __builtin_amdgcn_mfma_f32_16x16x32_f16(AV[0], P[1], acc[0][J1], 0, 0, 0); \
    acc[1][J0] = __builtin_amdgcn_mfma_f32_16x16x32_f16(AV[1], P[0], acc[1][J0], 0, 0, 0); \
    acc[1][J1] = __builtin_amdgcn_mfma_f32_16x16x32_f16(AV[1], P[1], acc[1][J1], 0, 0, 0); \
    __builtin_amdgcn_s_setprio(0);                                  \
  } while (0)

  LAV(av0, 0);                        // kt=0 V operands
  LBH(a0, 0);                         // kt=0 bpA (j0,j1)
  #pragma unroll 1
  for (int kt2 = 0; kt2 < 3; ++kt2) { // kt = {0,1},{2,3},{4,5}
    LAV(av1, 8192);                   // V kt+1
    LBH(b0, 1024);                    // bpB kt
    MM4(av0, a0, 0, 1);               // kt even, j0/j1
    LBH(a1, 2048);                    // bpA kt+1
    MM4(av0, b0, 2, 3);               // kt even, j2/j3
    LAV(av0, 16384);                  // V kt+2 (kt2=2 -> kt=6, in bounds)
    LBH(b1, 3072);                    // bpB kt+1
    MM4(av1, a1, 0, 1);               // kt odd, j0/j1
    LBH(a0, 4096);                    // bpA kt+2 (kt2=2 -> kt=6, in bounds)
    MM4(av1, b1, 2, 3);               // kt odd, j2/j3
    Bk += 16384; Ak += 4096;
  }
  // kt = 6,7 peeled (no dead prefetch past Vh2); a0 holds kt=6 bpA, av0 kt=6 V
  LAV(av1, 8192);                     // kt=7 V
  LBH(b0, 1024);                      // kt=6 bpB
  MM4(av0, a0, 0, 1);
  LBH(a1, 2048);                      // kt=7 bpA
  MM4(av0, b0, 2, 3);
  LBH(b1, 3072);                      // kt=7 bpB
  MM4(av1, a1, 0, 1);
  MM4(av1, b1, 2, 3);
#undef LAV
#undef LBH
#undef MM4

  // Epilogue (S^T). Lane (cl,q) holds, for patch row m = row0 + j*16 + cl,
  // scores of vocab cols v = c0w + i*16 + q*4 + r.
  // key_f = (score+1024)*512 = (v2+1024)*512 - 1024*acc
  float Cv[8];
  #pragma unroll
  for (int i = 0; i < 2; ++i) {
    const float4 vq = *(const float4*)(v2 + c0w + i * 16 + q * 4);
    #pragma unroll
    for (int r = 0; r < 4; ++r) Cv[i * 4 + r] = fmaf(vq[r], 512.0f, 524288.0f);
  }
  // Per-lane top-2 over this lane's 8 cols per j. NO cross-lane shuffles:
  // q-merge deferred to the LDS pass (top-2 union-fold is order-independent;
  // keys unique via embedded col -> bit-identical pk1/pk2).
  unsigned wk1[4], wk2[4];
  #pragma unroll
  for (int j = 0; j < 4; ++j) {
    unsigned K1 = 0xFFFFFFFFu, K2 = 0xFFFFFFFFu;
    #pragma unroll
    for (int i = 0; i < 2; ++i)
      #pragma unroll
      for (int r = 0; r < 4; ++r) {
        const unsigned key =
            ((unsigned)fmaf(-1024.0f, acc[i][j][r], Cv[i * 4 + r]) << 12) |
            (unsigned)(c0w + i * 16 + q * 4 + r);
        K2 = min(K2, max(K1, key));
        K1 = min(K1, key);
      }
    wk1[j] = K1; wk2[j] = K2;
  }
  // ---- merge via Af-as-scratch: scr1/scr2 [wid(8)][row(64)][q(4)] u32 ----
  // Write banks: (cl*4+q)%32 -> exactly 2-way aliasing = free (m136).
  __syncthreads();                    // all waves finished ds_reads of Af
  unsigned* scr1 = (unsigned*)Af;     // 8 KB
  unsigned* scr2 = scr1 + 2048;       // 8 KB
  #pragma unroll
  for (int j = 0; j < 4; ++j) {
    const int idx = wid * 256 + (j * 16 + cl) * 4 + q;
    scr1[idx] = wk1[j]; scr2[idx] = wk2[j];
  }
  __syncthreads();
  if (tid < 256) {
    const int pair = tid >> 6, row = tid & 63;   // pair 0..3 = wid pairs
    unsigned K1 = 0xFFFFFFFFu, K2 = 0xFFFFFFFFu;
    #pragma unroll
    for (int w = 0; w < 2; ++w) {
      const int base = (pair * 2 + w) * 256 + row * 4;
      #pragma unroll
      for (int qq = 0; qq < 4; ++qq) {
        const unsigned b1 = scr1[base + qq], b2 = scr2[base + qq];
        K2 = min(min(K2, b2), max(K1, b1));
        K1 = min(K1, b1);
      }
    }
    const int grp = sp * 4 + pair;               // 0..63
    pk1[(size_t)grp * M + row0 + row] = K1;
    pk2[(size_t)grp * M + row0 + row] = K2;
  }
}

// ---------------------------------------------------------------------------
// Kernel 3: merge NSPLIT partials -> token; flagged patches emit fp64-rescore
// candidate pairs. 4 waves each scan 16 splits for 64 patches, LDS merge,
// wave 0 finishes (flag path rereads pk, ~4% only).
// ---------------------------------------------------------------------------
__global__ __launch_bounds__(256) void reduce_gather_kernel(
    const unsigned* __restrict__ pk1, const unsigned* __restrict__ pk2,
    float* __restrict__ tok, unsigned long long* __restrict__ minkey,
    unsigned* __restrict__ pairs, int* __restrict__ paircount) {
  __shared__ unsigned r1[4][64], r2[4][64];
  const int tid = threadIdx.x;
  const int mo  = tid & 63;
  const int wid = tid >> 6;
  const int m = blockIdx.x * 64 + mo;
  unsigned K1 = 0xFFFFFFFFu, K2 = 0xFFFFFFFFu;
  for (int s = wid * 16; s < wid * 16 + 16; ++s) {
    const unsigned b1 = pk1[(size_t)s * M + m];
    const unsigned b2 = pk2[(size_t)s * M + m];
    K2 = min(min(K2, b2), max(K1, b1));
    K1 = min(K1, b1);
  }
  r1[wid][mo] = K1; r2[wid][mo] = K2;
  __syncthreads();
  if (tid < 64) {
    K1 = 0xFFFFFFFFu; K2 = 0xFFFFFFFFu;
    #pragma unroll
    for (int w = 0; w < 4; ++w) {
      const unsigned b1 = r1[w][mo], b2 = r2[w][mo];
      K2 = min(min(K2, b2), max(K1, b1));
      K1 = min(K1, b1);
    }
    tok[m] = (float)(K1 & 4095u);
    minkey[m] = 0xFFFFFFFFFFFFFFFFull;
    if ((int)(K2 >> 12) - (int)(K1 >> 12) <= QMARGIN) {
      const int th = (int)(K1 >> 12) + QMARGIN;
      int cnt = 0;
      for (int s = 0; s < NSPLIT; ++s) {
        const unsigned b1 = pk1[(size_t)s * M + m];
        const unsigned b2 = pk2[(size_t)s * M + m];
        cnt += ((int)(b2 >> 12) <= th) ? 64
             : (((int)(b1 >> 12) <= th) ? 1 : 0);
      }
      int base = atomicAdd(paircount, cnt);
      if (base + cnt <= PAIR_CAP) {
        const unsigned mh = (unsigned)m << 12;
        for (int s = 0; s < NSPLIT; ++s) {
          const unsigned b1 = pk1[(size_t)s * M + m];
          const unsigned b2 = pk2[(size_t)s * M + m];
          if ((int)(b2 >> 12) <= th) {        // group may hide a 3rd contender
            for (int r = 0; r < 64; ++r) pairs[base + r] = mh | (unsigned)(s * 64 + r);
            base += 64;
          } else if ((int)(b1 >> 12) <= th) { // only stored winner qualifies
            pairs[base++] = mh | (b1 & 4095u);
          }
        }
      }
    }
  }
}

// ---------------------------------------------------------------------------
// Kernel 4: exact fp64 rescore, one wave per pair, single pass.
// key = (bits(d2) & ~0xFFF) | row: atomicMin = argmin with low-index
// tie-break; 12 dropped mantissa bits = ~1e-9 abs tolerance (safe).
// ---------------------------------------------------------------------------
__global__ __launch_bounds__(256) void refine_score(
    const float* __restrict__ patches, const float* __restrict__ vocab,
    const unsigned* __restrict__ pairs, const int* __restrict__ paircount,
    unsigned long long* __restrict__ minkey) {
  const int lane = threadIdx.x & 63;
  const int gw = (blockIdx.x * 256 + threadIdx.x) >> 6;
  const int nw = (gridDim.x * 256) >> 6;
  int np = *paircount;
  if (np > PAIR_CAP) np = PAIR_CAP;
  for (int i = gw; i < np; i += nw) {
    const unsigned pr = pairs[i];
    const int m = pr >> 12, row = pr & 4095;
    const float4 pv = *(const float4*)(patches + (size_t)m * D + (lane << 2));
    const float4 vv = *(const float4*)(vocab + (size_t)row * D + (lane << 2));
    double acc = 0.0, df;
    df = (double)pv.x - (double)vv.x; acc = fma(df, df, acc);
    df = (double)pv.y - (double)vv.y; acc = fma(df, df, acc);
    df = (double)pv.z - (double)vv.z; acc = fma(df, df, acc);
    df = (double)pv.w - (double)vv.w; acc = fma(df, df, acc);
    #pragma unroll
    for (int off = 32; off > 0; off >>= 1) acc += __shfl_down(acc, off);
    if (lane == 0) {
      const unsigned long long key =
          ((unsigned long long)__double_as_longlong(acc) & ~0xFFFull) | (unsigned)row;
      atomicMin(&minkey[m], key);
    }
  }
}

// ---------------------------------------------------------------------------
// Kernel 5: write refined tokens (grid-stride over pairs; redundant same-value
// writes per flagged patch are benign).
// ---------------------------------------------------------------------------
__global__ __launch_bounds__(256) void refine_final(
    const unsigned* __restrict__ pairs, const int* __restrict__ paircount,
    const unsigned long long* __restrict__ minkey, float* __restrict__ tok) {
  int np = *paircount;
  if (np > PAIR_CAP) np = PAIR_CAP;
  for (int i = blockIdx.x * 256 + threadIdx.x; i < np; i += gridDim.x * 256) {
    const int m = pairs[i] >> 12;
    tok[m] = (float)(unsigned)(minkey[m] & 4095ull);
  }
}

// ---------------------------------------------------------------------------
extern "C" void kernel_launch(void* const* d_in, const int* in_sizes, int n_in,
                              void* d_out, int out_size, void* d_ws, size_t ws_size,
                              hipStream_t stream) {
  const float* images = (const float*)d_in[0];   // [64,256,256]
  const float* vocab  = (const float*)d_in[1];   // [4096,256]
  float* out     = (float*)d_out;
  float* patches = out;            // M*D floats
  float* tokens  = out + (size_t)M * D;

  // workspace layout (bytes):
  // Ah2 8MB | Vh2 2MB | v2 16KB | pk1 4MB | pk2 4MB | minkey 128KB |
  // paircount 64B | pairs 4MB   (~22.3 MB)
  char* ws = (char*)d_ws;
  _Float16* Ah2      = (_Float16*)(ws);
  _Float16* Vh2      = (_Float16*)(ws + 8388608);
  float*    v2       = (float*)   (ws + 10485760);
  unsigned* pk1      = (unsigned*)(ws + 10502144);
  unsigned* pk2      = (unsigned*)(ws + 14696448);
  unsigned long long* minkey = (unsigned long long*)(ws + 18890752);
  int*      paircount= (int*)     (ws + 19021824);
  unsigned* pairs    = (unsigned*)(ws + 19021888);

  prep_kernel<<<4096 + 1024, 256, 0, stream>>>(images, vocab, patches, Ah2,
                                               Vh2, v2, paircount);
  gemm_score_kernel<<<dim3(V / 256, M / 64), 512, 0, stream>>>(Ah2, Vh2, v2, pk1, pk2);
  reduce_gather_kernel<<<M / 64, 256, 0, stream>>>(pk1, pk2, tokens, minkey,
                                                   pairs, paircount);
  refine_score<<<2048, 256, 0, stream>>>(patches, vocab, pairs, paircount, minkey);
  refine_final<<<64, 256, 0, stream>>>(pairs, paircount, minkey, tokens);
}